// Round 4
// baseline (47.653 us; speedup 1.0000x reference)
//
#include <hip/hip_runtime.h>
#include <hip/hip_bf16.h>

#define SIG   1000
#define MROWS 8192
#define FK    512    // folded K (500 used, padded)
#define FW    1024   // fold buffer width: [ce(512) | ho(512)]
#define NPAD  1024   // GEMM N: group0 = even-bin (cos,sin) pairs, group1 = odd-bin
#define PSDK  512    // psd padded columns (500 used) -> head GEMM K
#define HN    192    // head GEMM padded N (141 used)
#define NOUT  141

using f32x4  = __attribute__((ext_vector_type(4))) float;
using short8 = __attribute__((ext_vector_type(8))) short;

__device__ inline ushort f2bf(float f) {
  union { float f; unsigned u; } v; v.f = f;
  unsigned u = v.u;
  unsigned r = (u + 0x7FFFu + ((u >> 16) & 1u)) >> 16;   // RNE
  return (ushort)r;
}

// Radix-2 fold: h[k] = x[r][k]*filt[k];
// fh[r][0..499]    = bf16(h[k] + h[k+500])  (even bins), pad 500..511 = 0
// fh[r][512..1011] = bf16(h[k] - h[k+500])  (odd bins),  pad 1012..1023 = 0
__global__ __launch_bounds__(256) void fold_k(
    const float* __restrict__ x, const float* __restrict__ filt,
    ushort* __restrict__ fh) {
  const int tid = threadIdx.x;
  const int r   = blockIdx.x * 2 + (tid >> 7);
  const int c   = tid & 127;               // float4 chunk within 512-col half
  ushort4 e = make_ushort4(0, 0, 0, 0);
  ushort4 o = make_ushort4(0, 0, 0, 0);
  if (c < 125) {
    const float4* xr = (const float4*)(x + (size_t)r * SIG);
    const float4* fr = (const float4*)filt;
    const float4 xl = xr[c],       fl = fr[c];
    const float4 xh = xr[c + 125], fhv = fr[c + 125];
    float lx = xl.x * fl.x, ly = xl.y * fl.y, lz = xl.z * fl.z, lw = xl.w * fl.w;
    float hx = xh.x * fhv.x, hy = xh.y * fhv.y, hz = xh.z * fhv.z, hw = xh.w * fhv.w;
    e.x = f2bf(lx + hx); e.y = f2bf(ly + hy); e.z = f2bf(lz + hz); e.w = f2bf(lw + hw);
    o.x = f2bf(lx - hx); o.y = f2bf(ly - hy); o.z = f2bf(lz - hz); o.w = f2bf(lw - hw);
  }
  ((ushort4*)(fh + (size_t)r * FW))[c]       = e;
  ((ushort4*)(fh + (size_t)r * FW + FK))[c]  = o;
}

// Merged weight-build (one launch): blocks [0,NPAD) -> Bt rows, [NPAD,NPAD+HN) -> W3p rows
//   Bt[n][k]: g=n>>9, cg=n&511, bin m=2*(cg>>1)+g; trig=cg&1 -> sin else cos of 2*pi*k*m/1000
//   W3p[n][k] = bf16(W3[n][k]) zero-padded to [HN][PSDK]
__global__ __launch_bounds__(128) void build_misc_k(
    const float* __restrict__ W3, ushort* __restrict__ Bt,
    ushort* __restrict__ W3p) {
  const int b = blockIdx.x;
  const int c = threadIdx.x;               // ushort4 chunk: k = 4c..4c+3
  if (b < NPAD) {
    const int cg = b & 511, g = b >> 9;
    ushort4 o = make_ushort4(0, 0, 0, 0);
    if (cg < 500) {
      const int m = 2 * (cg >> 1) + g;
      const int trig = cg & 1;
      const float C = 6.28318530717958647692f / 1000.0f;
      ushort v[4];
#pragma unroll
      for (int j = 0; j < 4; ++j) {
        int ph = ((4 * c + j) * m) % 1000;
        float ang = ph * C;
        v[j] = f2bf(trig ? __sinf(ang) : __cosf(ang));
      }
      o = make_ushort4(v[0], v[1], v[2], v[3]);
    }
    ((ushort4*)(Bt + (size_t)b * FK))[c] = o;
  } else {
    const int n = b - NPAD;
    ushort4 o = make_ushort4(0, 0, 0, 0);
    if (n < NOUT && c < 125) {             // 4c+3 <= 499
      const float4 w = *(const float4*)(W3 + (size_t)n * 500 + 4 * c);
      o.x = f2bf(w.x); o.y = f2bf(w.y); o.z = f2bf(w.z); o.w = f2bf(w.w);
    }
    ((ushort4*)(W3p + (size_t)n * PSDK))[c] = o;
  }
}

// Folded DFT GEMM + psd epilogue. M=8192, K=512, N=1024 (by: 0-3 even grp, 4-7 odd).
// 2-phase double-buffered: STAGE(t+1) issued before compute(t), one barrier per tile.
__global__ __launch_bounds__(256) void gemm_psd_k(
    const ushort* __restrict__ A, const ushort* __restrict__ Bt,
    ushort* __restrict__ psd) {
  __shared__ ushort lA[2][128 * 32];   // 2 x 8 KiB
  __shared__ ushort lB[2][128 * 32];   // 2 x 8 KiB
  const int tid  = threadIdx.x;
  const int wave = tid >> 6;
  const int lane = tid & 63;
  const int row0 = blockIdx.x * 128;
  const int n0   = blockIdx.y * 128;
  const int aoff = (blockIdx.y >= 4) ? FK : 0;   // ce vs ho half
  const int wm = (wave >> 1) * 64;
  const int wn = (wave & 1) * 64;
  const int lr = lane & 15;
  const int kg = (lane >> 4) * 8;

  // staging geometry: per wave 2 chunks of A + 2 of B (64 lanes x 16 B = 1 KiB each)
  const int sb0   = wave * 2048;
  const int off0  = sb0 + lane * 16;
  const int row_0 = off0 >> 6;
  const int kb_0  = (off0 & 63) >> 1;
  const int off1  = off0 + 1024;
  const int row_1 = off1 >> 6;
  const int kb_1  = (off1 & 63) >> 1;
  const ushort* gA0 = A  + (size_t)(row0 + row_0) * FW + aoff + kb_0;
  const ushort* gA1 = A  + (size_t)(row0 + row_1) * FW + aoff + kb_1;
  const ushort* gB0 = Bt + (size_t)(n0 + row_0) * FK + kb_0;
  const ushort* gB1 = Bt + (size_t)(n0 + row_1) * FK + kb_1;

  f32x4 acc[4][4] = {};

#define STAGE(buf, k0)                                                          \
  do {                                                                          \
    __builtin_amdgcn_global_load_lds(                                           \
        (const __attribute__((address_space(1))) void*)(gA0 + (k0)),            \
        (__attribute__((address_space(3))) void*)((char*)lA[buf] + sb0), 16, 0, 0); \
    __builtin_amdgcn_global_load_lds(                                           \
        (const __attribute__((address_space(1))) void*)(gB0 + (k0)),            \
        (__attribute__((address_space(3))) void*)((char*)lB[buf] + sb0), 16, 0, 0); \
    __builtin_amdgcn_global_load_lds(                                           \
        (const __attribute__((address_space(1))) void*)(gA1 + (k0)),            \
        (__attribute__((address_space(3))) void*)((char*)lA[buf] + sb0 + 1024), 16, 0, 0); \
    __builtin_amdgcn_global_load_lds(                                           \
        (const __attribute__((address_space(1))) void*)(gB1 + (k0)),            \
        (__attribute__((address_space(3))) void*)((char*)lB[buf] + sb0 + 1024), 16, 0, 0); \
  } while (0)

  STAGE(0, 0);
  __syncthreads();                 // vmcnt(0) drain + barrier: buf0 ready
  int cur = 0;
  for (int kt = 0; kt < FK / 32; ++kt) {
    if (kt + 1 < FK / 32) STAGE(cur ^ 1, (kt + 1) * 32);   // prefetch flies over MFMA
    short8 a[4], b[4];
    const ushort* baseA = lA[cur];
    const ushort* baseB = lB[cur];
#pragma unroll
    for (int m = 0; m < 4; ++m)
      a[m] = *(const short8*)&baseA[(wm + m * 16 + lr) * 32 + kg];
#pragma unroll
    for (int n = 0; n < 4; ++n)
      b[n] = *(const short8*)&baseB[(wn + n * 16 + lr) * 32 + kg];
#pragma unroll
    for (int m = 0; m < 4; ++m)
#pragma unroll
      for (int n = 0; n < 4; ++n)
        acc[m][n] = __builtin_amdgcn_mfma_f32_16x16x32_bf16(a[m], b[n], acc[m][n], 0, 0, 0);
    __syncthreads();               // drains prefetch (vmcnt) + ds_reads (lgkm)
    cur ^= 1;
  }
#undef STAGE

  // epilogue: C/D layout col=lane&15, row=(lane>>4)*4+j (m89/m91 verified)
  const int g = blockIdx.y >> 2;
  const int colpar = lane & 1;
#pragma unroll
  for (int m = 0; m < 4; ++m) {
#pragma unroll
    for (int n = 0; n < 4; ++n) {
#pragma unroll
      for (int j = 0; j < 4; ++j) {
        float v  = acc[m][n][j];
        float v2 = __shfl_xor(v, 1);             // sin partner of the pair
        if (!colpar) {
          int grow  = row0 + wm + m * 16 + (lane >> 4) * 4 + j;
          int cg    = ((n0 + wn + n * 16 + lr) & 511);
          int mbin  = (cg & ~1) + g;             // 2*pair + group
          psd[(size_t)grow * PSDK + mbin] = f2bf((v * v + v2 * v2) * 1e-6f);
        }
      }
    }
  }
}

// head: out[8192][141] = psd[:, :500] @ W3^T + b3 via bf16 MFMA.
// Tile 64(M) x 192(N), K=512, 2-phase double-buffered. Grid 128.
__global__ __launch_bounds__(256) void head_gemm_k(
    const ushort* __restrict__ psd, const ushort* __restrict__ W3p,
    const float* __restrict__ b3, float* __restrict__ out) {
  __shared__ ushort lA[2][64 * 32];    // 2 x 4 KiB
  __shared__ ushort lB[2][HN * 32];    // 2 x 12 KiB
  const int tid  = threadIdx.x;
  const int wave = tid >> 6;
  const int lane = tid & 63;
  const int row0 = blockIdx.x * 64;
  const int wm = (wave >> 1) * 32;
  const int wn = (wave & 1) * 96;
  const int lr = lane & 15;
  const int kg = (lane >> 4) * 8;

  // A: 1 chunk/wave; B: 3 chunks/wave
  const int offA  = wave * 1024 + lane * 16;
  const int rowA  = offA >> 6;
  const int kbA   = (offA & 63) >> 1;
  const ushort* gA = psd + (size_t)(row0 + rowA) * PSDK + kbA;
  const int offB0 = wave * 3072 + lane * 16;
  const int rowB0 = offB0 >> 6,          kbB0 = (offB0 & 63) >> 1;
  const int rowB1 = (offB0 + 1024) >> 6, kbB1 = ((offB0 + 1024) & 63) >> 1;
  const int rowB2 = (offB0 + 2048) >> 6, kbB2 = ((offB0 + 2048) & 63) >> 1;
  const ushort* gB0 = W3p + (size_t)rowB0 * PSDK + kbB0;
  const ushort* gB1 = W3p + (size_t)rowB1 * PSDK + kbB1;
  const ushort* gB2 = W3p + (size_t)rowB2 * PSDK + kbB2;

  f32x4 acc[2][6] = {};

#define HSTAGE(buf, k0)                                                         \
  do {                                                                          \
    __builtin_amdgcn_global_load_lds(                                           \
        (const __attribute__((address_space(1))) void*)(gA + (k0)),             \
        (__attribute__((address_space(3))) void*)((char*)lA[buf] + wave * 1024), 16, 0, 0); \
    __builtin_amdgcn_global_load_lds(                                           \
        (const __attribute__((address_space(1))) void*)(gB0 + (k0)),            \
        (__attribute__((address_space(3))) void*)((char*)lB[buf] + wave * 3072), 16, 0, 0); \
    __builtin_amdgcn_global_load_lds(                                           \
        (const __attribute__((address_space(1))) void*)(gB1 + (k0)),            \
        (__attribute__((address_space(3))) void*)((char*)lB[buf] + wave * 3072 + 1024), 16, 0, 0); \
    __builtin_amdgcn_global_load_lds(                                           \
        (const __attribute__((address_space(1))) void*)(gB2 + (k0)),            \
        (__attribute__((address_space(3))) void*)((char*)lB[buf] + wave * 3072 + 2048), 16, 0, 0); \
  } while (0)

  HSTAGE(0, 0);
  __syncthreads();
  int cur = 0;
  for (int kt = 0; kt < PSDK / 32; ++kt) {
    if (kt + 1 < PSDK / 32) HSTAGE(cur ^ 1, (kt + 1) * 32);
    short8 a[2], b[6];
    const ushort* baseA = lA[cur];
    const ushort* baseB = lB[cur];
#pragma unroll
    for (int m = 0; m < 2; ++m)
      a[m] = *(const short8*)&baseA[(wm + m * 16 + lr) * 32 + kg];
#pragma unroll
    for (int n = 0; n < 6; ++n)
      b[n] = *(const short8*)&baseB[(wn + n * 16 + lr) * 32 + kg];
#pragma unroll
    for (int m = 0; m < 2; ++m)
#pragma unroll
      for (int n = 0; n < 6; ++n)
        acc[m][n] = __builtin_amdgcn_mfma_f32_16x16x32_bf16(a[m], b[n], acc[m][n], 0, 0, 0);
    __syncthreads();
    cur ^= 1;
  }
#undef HSTAGE

#pragma unroll
  for (int m = 0; m < 2; ++m) {
#pragma unroll
    for (int n = 0; n < 6; ++n) {
#pragma unroll
      for (int j = 0; j < 4; ++j) {
        int gcol = wn + n * 16 + lr;
        if (gcol < NOUT) {
          int grow = row0 + wm + m * 16 + (lane >> 4) * 4 + j;
          out[(size_t)grow * NOUT + gcol] = acc[m][n][j] + b3[gcol];
        }
      }
    }
  }
}

extern "C" void kernel_launch(void* const* d_in, const int* in_sizes, int n_in,
                              void* d_out, int out_size, void* d_ws, size_t ws_size,
                              hipStream_t stream) {
  const float* x    = (const float*)d_in[0];
  const float* filt = (const float*)d_in[1];
  // d_in[2] (Wf), d_in[3] (Wfc) unused: DFT weights synthesized on device;
  // r2 = r1, i2 = -i1 algebraically so Wfc's GEMM is redundant.
  const float* W3   = (const float*)d_in[4];
  const float* b3   = (const float*)d_in[5];
  float* out = (float*)d_out;

  char* ws = (char*)d_ws;
  ushort* fh  = (ushort*)ws;                                     // 16 MiB
  ushort* Bt  = (ushort*)(ws + (size_t)MROWS * FW * 2);          // +1 MiB
  ushort* psd = (ushort*)(ws + (size_t)MROWS * FW * 2
                             + (size_t)NPAD * FK * 2);           // +8 MiB
  ushort* W3p = (ushort*)(ws + (size_t)MROWS * FW * 2
                             + (size_t)NPAD * FK * 2
                             + (size_t)MROWS * PSDK * 2);        // +192 KiB

  fold_k<<<MROWS / 2, 256, 0, stream>>>(x, filt, fh);
  build_misc_k<<<NPAD + HN, 128, 0, stream>>>(W3, Bt, W3p);
  gemm_psd_k<<<dim3(MROWS / 128, NPAD / 128), 256, 0, stream>>>(fh, Bt, psd);
  head_gemm_k<<<MROWS / 64, 256, 0, stream>>>(psd, W3p, b3, out);
}

// Round 5
// 43.517 us; speedup vs baseline: 1.0951x; 1.0951x over previous
//
#include <hip/hip_runtime.h>
#include <hip/hip_bf16.h>

#define SIG   1000
#define MROWS 8192
#define FK    512    // folded K (500 used, padded)
#define FW    1024   // fold buffer width: [ce(512) | ho(512)]
#define NPAD  1024   // GEMM N: group0 = even-bin (cos,sin) pairs, group1 = odd-bin
#define PSDK  512    // psd padded columns (500 used) -> head GEMM K
#define HN    192    // head GEMM padded N (141 used)
#define NOUT  141
#define NT    16     // K-tiles per GEMM (512/32)

using f32x4  = __attribute__((ext_vector_type(4))) float;
using short8 = __attribute__((ext_vector_type(8))) short;

__device__ inline ushort f2bf(float f) {
  union { float f; unsigned u; } v; v.f = f;
  unsigned u = v.u;
  unsigned r = (u + 0x7FFFu + ((u >> 16) & 1u)) >> 16;   // RNE
  return (ushort)r;
}

// Merged prep: blocks [0,4096) do the radix-2 fold (2 rows each);
// blocks [4096, 4096+608) build Bt / W3p (2 weight-rows each).
__global__ __launch_bounds__(256) void prep_k(
    const float* __restrict__ x, const float* __restrict__ filt,
    const float* __restrict__ W3, ushort* __restrict__ fh,
    ushort* __restrict__ Bt, ushort* __restrict__ W3p) {
  const int tid = threadIdx.x;
  const int blk = blockIdx.x;
  if (blk < MROWS / 2) {
    // ---- fold: h[k]=x*filt; fh[r][k]=h[k]+h[k+500], fh[r][512+k]=h[k]-h[k+500]
    const int r = blk * 2 + (tid >> 7);
    const int c = tid & 127;               // float4 chunk within 512-col half
    ushort4 e = make_ushort4(0, 0, 0, 0);
    ushort4 o = make_ushort4(0, 0, 0, 0);
    if (c < 125) {
      const float4* xr = (const float4*)(x + (size_t)r * SIG);
      const float4* fr = (const float4*)filt;
      const float4 xl = xr[c],       fl = fr[c];
      const float4 xh = xr[c + 125], fv = fr[c + 125];
      float lx = xl.x * fl.x, ly = xl.y * fl.y, lz = xl.z * fl.z, lw = xl.w * fl.w;
      float hx = xh.x * fv.x, hy = xh.y * fv.y, hz = xh.z * fv.z, hw = xh.w * fv.w;
      e.x = f2bf(lx + hx); e.y = f2bf(ly + hy); e.z = f2bf(lz + hz); e.w = f2bf(lw + hw);
      o.x = f2bf(lx - hx); o.y = f2bf(ly - hy); o.z = f2bf(lz - hz); o.w = f2bf(lw - hw);
    }
    ((ushort4*)(fh + (size_t)r * FW))[c]      = e;
    ((ushort4*)(fh + (size_t)r * FW + FK))[c] = o;
  } else {
    // ---- weight build: rows [0,1024) -> Bt, [1024,1216) -> W3p
    const int row = (blk - MROWS / 2) * 2 + (tid >> 7);
    const int c   = tid & 127;             // ushort4 chunk: k = 4c..4c+3
    if (row < NPAD) {
      const int cg = row & 511, g = row >> 9;
      ushort4 o = make_ushort4(0, 0, 0, 0);
      if (cg < 500) {
        const int m = 2 * (cg >> 1) + g;
        const int trig = cg & 1;
        const float C = 6.28318530717958647692f / 1000.0f;
        ushort v[4];
#pragma unroll
        for (int j = 0; j < 4; ++j) {
          int ph = ((4 * c + j) * m) % 1000;
          float ang = ph * C;
          v[j] = f2bf(trig ? __sinf(ang) : __cosf(ang));
        }
        o = make_ushort4(v[0], v[1], v[2], v[3]);
      }
      ((ushort4*)(Bt + (size_t)row * FK))[c] = o;
    } else {
      const int n = row - NPAD;
      ushort4 o = make_ushort4(0, 0, 0, 0);
      if (n < NOUT && c < 125) {           // 4c+3 <= 499
        const float4 w = *(const float4*)(W3 + (size_t)n * 500 + 4 * c);
        o.x = f2bf(w.x); o.y = f2bf(w.y); o.z = f2bf(w.z); o.w = f2bf(w.w);
      }
      ((ushort4*)(W3p + (size_t)n * PSDK))[c] = o;
    }
  }
}

// Folded DFT GEMM + psd epilogue. M=8192, K=512, N=1024 (by: 0-3 even grp, 4-7 odd).
// Depth-2 pipeline: 3 LDS buffers, counted s_waitcnt vmcnt(4) across raw s_barrier.
__global__ __launch_bounds__(256) void gemm_psd_k(
    const ushort* __restrict__ A, const ushort* __restrict__ Bt,
    ushort* __restrict__ psd) {
  __shared__ ushort lA[3][128 * 32];   // 3 x 8 KiB
  __shared__ ushort lB[3][128 * 32];   // 3 x 8 KiB
  const int tid  = threadIdx.x;
  const int wave = tid >> 6;
  const int lane = tid & 63;
  const int row0 = blockIdx.x * 128;
  const int n0   = blockIdx.y * 128;
  const int aoff = (blockIdx.y >= 4) ? FK : 0;   // ce vs ho half
  const int wm = (wave >> 1) * 64;
  const int wn = (wave & 1) * 64;
  const int lr = lane & 15;
  const int kg = (lane >> 4) * 8;

  // staging geometry: per wave 2 chunks of A + 2 of B (64 lanes x 16 B = 1 KiB each)
  const int sb0   = wave * 2048;
  const int off0  = sb0 + lane * 16;
  const int row_0 = off0 >> 6;
  const int kb_0  = (off0 & 63) >> 1;
  const int off1  = off0 + 1024;
  const int row_1 = off1 >> 6;
  const int kb_1  = (off1 & 63) >> 1;
  const ushort* gA0 = A  + (size_t)(row0 + row_0) * FW + aoff + kb_0;
  const ushort* gA1 = A  + (size_t)(row0 + row_1) * FW + aoff + kb_1;
  const ushort* gB0 = Bt + (size_t)(n0 + row_0) * FK + kb_0;
  const ushort* gB1 = Bt + (size_t)(n0 + row_1) * FK + kb_1;

  f32x4 acc[4][4] = {};

#define STAGE(buf, k0)                                                          \
  do {                                                                          \
    __builtin_amdgcn_global_load_lds(                                           \
        (const __attribute__((address_space(1))) void*)(gA0 + (k0)),            \
        (__attribute__((address_space(3))) void*)((char*)lA[buf] + sb0), 16, 0, 0); \
    __builtin_amdgcn_global_load_lds(                                           \
        (const __attribute__((address_space(1))) void*)(gB0 + (k0)),            \
        (__attribute__((address_space(3))) void*)((char*)lB[buf] + sb0), 16, 0, 0); \
    __builtin_amdgcn_global_load_lds(                                           \
        (const __attribute__((address_space(1))) void*)(gA1 + (k0)),            \
        (__attribute__((address_space(3))) void*)((char*)lA[buf] + sb0 + 1024), 16, 0, 0); \
    __builtin_amdgcn_global_load_lds(                                           \
        (const __attribute__((address_space(1))) void*)(gB1 + (k0)),            \
        (__attribute__((address_space(3))) void*)((char*)lB[buf] + sb0 + 1024), 16, 0, 0); \
  } while (0)

  STAGE(0, 0);
  STAGE(1, 32);
  asm volatile("s_waitcnt vmcnt(4)" ::: "memory");   // buf0 ready, buf1 in flight
  __builtin_amdgcn_s_barrier();

#pragma unroll
  for (int kt = 0; kt < NT; ++kt) {
    const int cur = kt % 3;
    if (kt + 2 < NT) STAGE((kt + 2) % 3, (kt + 2) * 32);
    short8 a[4], b[4];
    const ushort* baseA = lA[cur];
    const ushort* baseB = lB[cur];
#pragma unroll
    for (int m = 0; m < 4; ++m)
      a[m] = *(const short8*)&baseA[(wm + m * 16 + lr) * 32 + kg];
#pragma unroll
    for (int n = 0; n < 4; ++n)
      b[n] = *(const short8*)&baseB[(wn + n * 16 + lr) * 32 + kg];
#pragma unroll
    for (int m = 0; m < 4; ++m)
#pragma unroll
      for (int n = 0; n < 4; ++n)
        acc[m][n] = __builtin_amdgcn_mfma_f32_16x16x32_bf16(a[m], b[n], acc[m][n], 0, 0, 0);
    if (kt < NT - 1) {
      if (kt + 2 < NT)
        asm volatile("s_waitcnt vmcnt(4) lgkmcnt(0)" ::: "memory");  // next buf ready, newest stays in flight
      else
        asm volatile("s_waitcnt vmcnt(0) lgkmcnt(0)" ::: "memory");  // tail drain
      __builtin_amdgcn_s_barrier();
    }
  }
#undef STAGE

  // epilogue: C/D layout col=lane&15, row=(lane>>4)*4+j (m89/m91 verified)
  const int g = blockIdx.y >> 2;
  const int colpar = lane & 1;
#pragma unroll
  for (int m = 0; m < 4; ++m) {
#pragma unroll
    for (int n = 0; n < 4; ++n) {
#pragma unroll
      for (int j = 0; j < 4; ++j) {
        float v  = acc[m][n][j];
        float v2 = __shfl_xor(v, 1);             // sin partner of the pair
        if (!colpar) {
          int grow  = row0 + wm + m * 16 + (lane >> 4) * 4 + j;
          int cg    = ((n0 + wn + n * 16 + lr) & 511);
          int mbin  = (cg & ~1) + g;             // 2*pair + group
          psd[(size_t)grow * PSDK + mbin] = f2bf((v * v + v2 * v2) * 1e-6f);
        }
      }
    }
  }
}

// head: out[8192][141] = psd[:, :500] @ W3^T + b3 via bf16 MFMA.
// Tile 64(M) x 192(N), K=512. Depth-2 pipeline, 3 buffers. Grid 128.
__global__ __launch_bounds__(256) void head_gemm_k(
    const ushort* __restrict__ psd, const ushort* __restrict__ W3p,
    const float* __restrict__ b3, float* __restrict__ out) {
  __shared__ ushort lA[3][64 * 32];    // 3 x 4 KiB
  __shared__ ushort lB[3][HN * 32];    // 3 x 12 KiB
  const int tid  = threadIdx.x;
  const int wave = tid >> 6;
  const int lane = tid & 63;
  const int row0 = blockIdx.x * 64;
  const int wm = (wave >> 1) * 32;
  const int wn = (wave & 1) * 96;
  const int lr = lane & 15;
  const int kg = (lane >> 4) * 8;

  // A: 1 chunk/wave; B: 3 chunks/wave
  const int offA  = wave * 1024 + lane * 16;
  const int rowA  = offA >> 6;
  const int kbA   = (offA & 63) >> 1;
  const ushort* gA = psd + (size_t)(row0 + rowA) * PSDK + kbA;
  const int offB0 = wave * 3072 + lane * 16;
  const int rowB0 = offB0 >> 6,          kbB0 = (offB0 & 63) >> 1;
  const int rowB1 = (offB0 + 1024) >> 6, kbB1 = ((offB0 + 1024) & 63) >> 1;
  const int rowB2 = (offB0 + 2048) >> 6, kbB2 = ((offB0 + 2048) & 63) >> 1;
  const ushort* gB0 = W3p + (size_t)rowB0 * PSDK + kbB0;
  const ushort* gB1 = W3p + (size_t)rowB1 * PSDK + kbB1;
  const ushort* gB2 = W3p + (size_t)rowB2 * PSDK + kbB2;

  f32x4 acc[2][6] = {};

#define HSTAGE(buf, k0)                                                         \
  do {                                                                          \
    __builtin_amdgcn_global_load_lds(                                           \
        (const __attribute__((address_space(1))) void*)(gA + (k0)),             \
        (__attribute__((address_space(3))) void*)((char*)lA[buf] + wave * 1024), 16, 0, 0); \
    __builtin_amdgcn_global_load_lds(                                           \
        (const __attribute__((address_space(1))) void*)(gB0 + (k0)),            \
        (__attribute__((address_space(3))) void*)((char*)lB[buf] + wave * 3072), 16, 0, 0); \
    __builtin_amdgcn_global_load_lds(                                           \
        (const __attribute__((address_space(1))) void*)(gB1 + (k0)),            \
        (__attribute__((address_space(3))) void*)((char*)lB[buf] + wave * 3072 + 1024), 16, 0, 0); \
    __builtin_amdgcn_global_load_lds(                                           \
        (const __attribute__((address_space(1))) void*)(gB2 + (k0)),            \
        (__attribute__((address_space(3))) void*)((char*)lB[buf] + wave * 3072 + 2048), 16, 0, 0); \
  } while (0)

  HSTAGE(0, 0);
  HSTAGE(1, 32);
  asm volatile("s_waitcnt vmcnt(4)" ::: "memory");
  __builtin_amdgcn_s_barrier();

#pragma unroll
  for (int kt = 0; kt < NT; ++kt) {
    const int cur = kt % 3;
    if (kt + 2 < NT) HSTAGE((kt + 2) % 3, (kt + 2) * 32);
    short8 a[2], b[6];
    const ushort* baseA = lA[cur];
    const ushort* baseB = lB[cur];
#pragma unroll
    for (int m = 0; m < 2; ++m)
      a[m] = *(const short8*)&baseA[(wm + m * 16 + lr) * 32 + kg];
#pragma unroll
    for (int n = 0; n < 6; ++n)
      b[n] = *(const short8*)&baseB[(wn + n * 16 + lr) * 32 + kg];
#pragma unroll
    for (int m = 0; m < 2; ++m)
#pragma unroll
      for (int n = 0; n < 6; ++n)
        acc[m][n] = __builtin_amdgcn_mfma_f32_16x16x32_bf16(a[m], b[n], acc[m][n], 0, 0, 0);
    if (kt < NT - 1) {
      if (kt + 2 < NT)
        asm volatile("s_waitcnt vmcnt(4) lgkmcnt(0)" ::: "memory");
      else
        asm volatile("s_waitcnt vmcnt(0) lgkmcnt(0)" ::: "memory");
      __builtin_amdgcn_s_barrier();
    }
  }
#undef HSTAGE

#pragma unroll
  for (int m = 0; m < 2; ++m) {
#pragma unroll
    for (int n = 0; n < 6; ++n) {
#pragma unroll
      for (int j = 0; j < 4; ++j) {
        int gcol = wn + n * 16 + lr;
        if (gcol < NOUT) {
          int grow = row0 + wm + m * 16 + (lane >> 4) * 4 + j;
          out[(size_t)grow * NOUT + gcol] = acc[m][n][j] + b3[gcol];
        }
      }
    }
  }
}

extern "C" void kernel_launch(void* const* d_in, const int* in_sizes, int n_in,
                              void* d_out, int out_size, void* d_ws, size_t ws_size,
                              hipStream_t stream) {
  const float* x    = (const float*)d_in[0];
  const float* filt = (const float*)d_in[1];
  // d_in[2] (Wf), d_in[3] (Wfc) unused: DFT weights synthesized on device;
  // r2 = r1, i2 = -i1 algebraically so Wfc's GEMM is redundant.
  const float* W3   = (const float*)d_in[4];
  const float* b3   = (const float*)d_in[5];
  float* out = (float*)d_out;

  char* ws = (char*)d_ws;
  ushort* fh  = (ushort*)ws;                                     // 16 MiB
  ushort* Bt  = (ushort*)(ws + (size_t)MROWS * FW * 2);          // +1 MiB
  ushort* psd = (ushort*)(ws + (size_t)MROWS * FW * 2
                             + (size_t)NPAD * FK * 2);           // +8 MiB
  ushort* W3p = (ushort*)(ws + (size_t)MROWS * FW * 2
                             + (size_t)NPAD * FK * 2
                             + (size_t)MROWS * PSDK * 2);        // +192 KiB

  prep_k<<<MROWS / 2 + 608, 256, 0, stream>>>(x, filt, W3, fh, Bt, W3p);
  gemm_psd_k<<<dim3(MROWS / 128, NPAD / 128), 256, 0, stream>>>(fh, Bt, psd);
  head_gemm_k<<<MROWS / 64, 256, 0, stream>>>(psd, W3p, b3, out);
}

// Round 7
// 39.735 us; speedup vs baseline: 1.1993x; 1.0952x over previous
//
#include <hip/hip_runtime.h>
#include <hip/hip_bf16.h>

#define SIG   1000
#define MROWS 8192
#define FK    512    // folded K (500 used, padded)
#define FW    1024   // fold buffer width: [ce(512) | ho(512)]
#define NPAD  1024   // GEMM N: group0 = even-bin (cos,sin) pairs, group1 = odd-bin
#define PSDK  512    // psd padded columns (500 used) -> head GEMM K
#define HN    192    // head GEMM padded N (141 used)
#define NOUT  141
#define NT    16     // K-tiles per GEMM (512/32)

using f32x4  = __attribute__((ext_vector_type(4))) float;
using short8 = __attribute__((ext_vector_type(8))) short;

__device__ inline ushort f2bf(float f) {
  union { float f; unsigned u; } v; v.f = f;
  unsigned u = v.u;
  unsigned r = (u + 0x7FFFu + ((u >> 16) & 1u)) >> 16;   // RNE
  return (ushort)r;
}

// Rule-#18 hardened pipeline boundary: nothing (MFMA, ds_read, global_load_lds)
// may be scheduled across the waitcnt+barrier pair in either direction.
#define SYNC_BOUNDARY(WAITSTR)                         \
  do {                                                 \
    __builtin_amdgcn_sched_barrier(0);                 \
    asm volatile(WAITSTR ::: "memory");                \
    __builtin_amdgcn_s_barrier();                      \
    __builtin_amdgcn_sched_barrier(0);                 \
  } while (0)

// Merged prep: blocks [0,4096) do the radix-2 fold (2 rows each);
// blocks [4096, 4096+608) build Bt / W3p (2 weight-rows each).
__global__ __launch_bounds__(256) void prep_k(
    const float* __restrict__ x, const float* __restrict__ filt,
    const float* __restrict__ W3, ushort* __restrict__ fh,
    ushort* __restrict__ Bt, ushort* __restrict__ W3p) {
  const int tid = threadIdx.x;
  const int blk = blockIdx.x;
  if (blk < MROWS / 2) {
    // ---- fold: h[k]=x*filt; fh[r][k]=h[k]+h[k+500], fh[r][512+k]=h[k]-h[k+500]
    const int r = blk * 2 + (tid >> 7);
    const int c = tid & 127;               // float4 chunk within 512-col half
    ushort4 e = make_ushort4(0, 0, 0, 0);
    ushort4 o = make_ushort4(0, 0, 0, 0);
    if (c < 125) {
      const float4* xr = (const float4*)(x + (size_t)r * SIG);
      const float4* fr = (const float4*)filt;
      const float4 xl = xr[c],       fl = fr[c];
      const float4 xh = xr[c + 125], fv = fr[c + 125];
      float lx = xl.x * fl.x, ly = xl.y * fl.y, lz = xl.z * fl.z, lw = xl.w * fl.w;
      float hx = xh.x * fv.x, hy = xh.y * fv.y, hz = xh.z * fv.z, hw = xh.w * fv.w;
      e.x = f2bf(lx + hx); e.y = f2bf(ly + hy); e.z = f2bf(lz + hz); e.w = f2bf(lw + hw);
      o.x = f2bf(lx - hx); o.y = f2bf(ly - hy); o.z = f2bf(lz - hz); o.w = f2bf(lw - hw);
    }
    ((ushort4*)(fh + (size_t)r * FW))[c]      = e;
    ((ushort4*)(fh + (size_t)r * FW + FK))[c] = o;
  } else {
    // ---- weight build: rows [0,1024) -> Bt, [1024,1216) -> W3p
    const int row = (blk - MROWS / 2) * 2 + (tid >> 7);
    const int c   = tid & 127;             // ushort4 chunk: k = 4c..4c+3
    if (row < NPAD) {
      const int cg = row & 511, g = row >> 9;
      ushort4 o = make_ushort4(0, 0, 0, 0);
      if (cg < 500) {
        const int m = 2 * (cg >> 1) + g;
        const int trig = cg & 1;
        const float C = 6.28318530717958647692f / 1000.0f;
        ushort v[4];
#pragma unroll
        for (int j = 0; j < 4; ++j) {
          int ph = ((4 * c + j) * m) % 1000;
          float ang = ph * C;
          v[j] = f2bf(trig ? __sinf(ang) : __cosf(ang));
        }
        o = make_ushort4(v[0], v[1], v[2], v[3]);
      }
      ((ushort4*)(Bt + (size_t)row * FK))[c] = o;
    } else {
      const int n = row - NPAD;
      ushort4 o = make_ushort4(0, 0, 0, 0);
      if (n < NOUT && c < 125) {           // 4c+3 <= 499
        const float4 w = *(const float4*)(W3 + (size_t)n * 500 + 4 * c);
        o.x = f2bf(w.x); o.y = f2bf(w.y); o.z = f2bf(w.z); o.w = f2bf(w.w);
      }
      ((ushort4*)(W3p + (size_t)n * PSDK))[c] = o;
    }
  }
}

// Folded DFT GEMM + psd epilogue. M=8192, K=512, N=1024.
// 64x128 tile, grid 1024 (4 blocks/CU), 4 waves (wave 32x64 = 2x4 frags).
// Depth-2 pipeline: 3 LDS buffers, counted s_waitcnt vmcnt(3) across s_barrier,
// every boundary sched_barrier(0)-pinned (rule #18).
__global__ __launch_bounds__(256, 4) void gemm_psd_k(
    const ushort* __restrict__ A, const ushort* __restrict__ Bt,
    ushort* __restrict__ psd) {
  __shared__ ushort lA[3][64 * 32];    // 3 x 4 KiB
  __shared__ ushort lB[3][128 * 32];   // 3 x 8 KiB
  const int tid  = threadIdx.x;
  const int wave = tid >> 6;
  const int lane = tid & 63;
  // bijective XCD swizzle: grid 1024 = 8 xcd x 128; 16 bx-panels per XCD
  const int id  = blockIdx.x;
  const int xcd = id & 7, rr = id >> 3;
  const int bx  = xcd * 16 + (rr & 15);      // [0,128)
  const int by  = rr >> 4;                   // [0,8)
  const int row0 = bx * 64;
  const int n0   = by * 128;
  const int aoff = (by >= 4) ? FK : 0;       // ce vs ho half
  const int wm = (wave >> 1) * 32;
  const int wn = (wave & 1) * 64;
  const int lr = lane & 15;
  const int kg = (lane >> 4) * 8;

  // staging: 12 chunks of 1 KiB (A:0-3, B:0-7); wave w stages chunks 3w..3w+2
  const ushort* gs[3];
  int doff[3], isa[3];
#pragma unroll
  for (int j = 0; j < 3; ++j) {
    const int i   = wave * 3 + j;
    const int ia  = (i < 4);
    const int idx = ia ? i : i - 4;
    const int off = idx * 1024 + lane * 16;
    const int row = off >> 6;
    const int kb  = (off & 63) >> 1;
    gs[j]   = ia ? (A  + (size_t)(row0 + row) * FW + aoff + kb)
                 : (Bt + (size_t)(n0   + row) * FK + kb);
    doff[j] = idx * 1024;
    isa[j]  = ia;
  }

  auto STAGE = [&](int buf, int k0) {
#pragma unroll
    for (int j = 0; j < 3; ++j) {
      char* db = (isa[j] ? (char*)lA[buf] : (char*)lB[buf]) + doff[j];
      __builtin_amdgcn_global_load_lds(
          (const __attribute__((address_space(1))) void*)(gs[j] + k0),
          (__attribute__((address_space(3))) void*)db, 16, 0, 0);
    }
  };

  f32x4 acc[2][4] = {};

  STAGE(0, 0);
  STAGE(1, 32);
  SYNC_BOUNDARY("s_waitcnt vmcnt(3)");   // buf0 ready, buf1 in flight

#pragma unroll
  for (int kt = 0; kt < NT; ++kt) {
    const int cur = kt % 3;
    if (kt + 2 < NT) STAGE((kt + 2) % 3, (kt + 2) * 32);
    short8 a[2], b[4];
    const ushort* baseA = lA[cur];
    const ushort* baseB = lB[cur];
#pragma unroll
    for (int m = 0; m < 2; ++m)
      a[m] = *(const short8*)&baseA[(wm + m * 16 + lr) * 32 + kg];
#pragma unroll
    for (int n = 0; n < 4; ++n)
      b[n] = *(const short8*)&baseB[(wn + n * 16 + lr) * 32 + kg];
#pragma unroll
    for (int m = 0; m < 2; ++m)
#pragma unroll
      for (int n = 0; n < 4; ++n)
        acc[m][n] = __builtin_amdgcn_mfma_f32_16x16x32_bf16(a[m], b[n], acc[m][n], 0, 0, 0);
    if (kt < NT - 1) {
      if (kt + 2 < NT)
        SYNC_BOUNDARY("s_waitcnt vmcnt(3) lgkmcnt(0)");  // next buf ready, newest in flight
      else
        SYNC_BOUNDARY("s_waitcnt vmcnt(0) lgkmcnt(0)");  // tail drain
    }
  }

  // epilogue: C/D layout col=lane&15, row=(lane>>4)*4+j (m89/m91 verified)
  const int g = by >> 2;
  const int colpar = lane & 1;
#pragma unroll
  for (int m = 0; m < 2; ++m) {
#pragma unroll
    for (int n = 0; n < 4; ++n) {
#pragma unroll
      for (int j = 0; j < 4; ++j) {
        float v  = acc[m][n][j];
        float v2 = __shfl_xor(v, 1);             // sin partner of the pair
        if (!colpar) {
          int grow = row0 + wm + m * 16 + (lane >> 4) * 4 + j;
          int cg   = ((n0 + wn + n * 16 + lr) & 511);
          int mbin = (cg & ~1) + g;              // 2*pair + group
          psd[(size_t)grow * PSDK + mbin] = f2bf((v * v + v2 * v2) * 1e-6f);
        }
      }
    }
  }
}

// head: out[8192][141] = psd[:, :500] @ W3^T + b3 via bf16 MFMA.
// 16x192 tile, grid 512 (2 blocks/CU), 4 waves (wave 16x48 = 1x3 frags).
// Same depth-2 pipeline, rule-#18 pinned boundaries.
__global__ __launch_bounds__(256, 2) void head_gemm_k(
    const ushort* __restrict__ psd, const ushort* __restrict__ W3p,
    const float* __restrict__ b3, float* __restrict__ out) {
  __shared__ ushort lA[3][16 * 32];    // 3 x 1 KiB
  __shared__ ushort lB[3][HN * 32];    // 3 x 12 KiB
  const int tid  = threadIdx.x;
  const int wave = tid >> 6;
  const int lane = tid & 63;
  const int row0 = blockIdx.x * 16;
  const int wn = wave * 48;
  const int lr = lane & 15;
  const int kg = (lane >> 4) * 8;

  // staging: 13 chunks (A:1, B:12); wave w -> chunks {w, w+4, w+8, w+12} (<13)
  const ushort* gs[4];
  int doff[4], isa[4], valid[4];
#pragma unroll
  for (int j = 0; j < 4; ++j) {
    const int i = wave + 4 * j;
    valid[j] = (i < 13);
    const int ia  = (i == 0);
    const int idx = ia ? 0 : (i - 1);
    const int off = (ia ? 0 : idx * 1024) + lane * 16;
    const int row = off >> 6;
    const int kb  = (off & 63) >> 1;
    gs[j]   = ia ? (psd + (size_t)(row0 + row) * PSDK + kb)
                 : (W3p + (size_t)row * PSDK + kb);
    doff[j] = ia ? 0 : idx * 1024;
    isa[j]  = ia;
  }

  auto HSTAGE = [&](int buf, int k0) {
#pragma unroll
    for (int j = 0; j < 4; ++j) {
      if (valid[j]) {
        char* db = (isa[j] ? (char*)lA[buf] : (char*)lB[buf]) + doff[j];
        __builtin_amdgcn_global_load_lds(
            (const __attribute__((address_space(1))) void*)(gs[j] + k0),
            (__attribute__((address_space(3))) void*)db, 16, 0, 0);
      }
    }
  };

  f32x4 acc[3] = {};

  HSTAGE(0, 0);
  HSTAGE(1, 32);
  // wave 0 stages 4 chunks/buffer, waves 1-3 stage 3 (wave-uniform branch)
  __builtin_amdgcn_sched_barrier(0);
  if (wave == 0) asm volatile("s_waitcnt vmcnt(4)" ::: "memory");
  else           asm volatile("s_waitcnt vmcnt(3)" ::: "memory");
  __builtin_amdgcn_s_barrier();
  __builtin_amdgcn_sched_barrier(0);

#pragma unroll
  for (int kt = 0; kt < NT; ++kt) {
    const int cur = kt % 3;
    if (kt + 2 < NT) HSTAGE((kt + 2) % 3, (kt + 2) * 32);
    short8 a, b[3];
    const ushort* baseA = lA[cur];
    const ushort* baseB = lB[cur];
    a = *(const short8*)&baseA[lr * 32 + kg];
#pragma unroll
    for (int n = 0; n < 3; ++n)
      b[n] = *(const short8*)&baseB[(wn + n * 16 + lr) * 32 + kg];
#pragma unroll
    for (int n = 0; n < 3; ++n)
      acc[n] = __builtin_amdgcn_mfma_f32_16x16x32_bf16(a, b[n], acc[n], 0, 0, 0);
    if (kt < NT - 1) {
      __builtin_amdgcn_sched_barrier(0);
      if (kt + 2 < NT) {
        if (wave == 0) asm volatile("s_waitcnt vmcnt(4) lgkmcnt(0)" ::: "memory");
        else           asm volatile("s_waitcnt vmcnt(3) lgkmcnt(0)" ::: "memory");
      } else {
        asm volatile("s_waitcnt vmcnt(0) lgkmcnt(0)" ::: "memory");
      }
      __builtin_amdgcn_s_barrier();
      __builtin_amdgcn_sched_barrier(0);
    }
  }

#pragma unroll
  for (int n = 0; n < 3; ++n) {
#pragma unroll
    for (int j = 0; j < 4; ++j) {
      int gcol = wn + n * 16 + lr;
      if (gcol < NOUT) {
        int grow = row0 + (lane >> 4) * 4 + j;
        out[(size_t)grow * NOUT + gcol] = acc[n][j] + b3[gcol];
      }
    }
  }
}

extern "C" void kernel_launch(void* const* d_in, const int* in_sizes, int n_in,
                              void* d_out, int out_size, void* d_ws, size_t ws_size,
                              hipStream_t stream) {
  const float* x    = (const float*)d_in[0];
  const float* filt = (const float*)d_in[1];
  // d_in[2] (Wf), d_in[3] (Wfc) unused: DFT weights synthesized on device;
  // r2 = r1, i2 = -i1 algebraically so Wfc's GEMM is redundant.
  const float* W3   = (const float*)d_in[4];
  const float* b3   = (const float*)d_in[5];
  float* out = (float*)d_out;

  char* ws = (char*)d_ws;
  ushort* fh  = (ushort*)ws;                                     // 16 MiB
  ushort* Bt  = (ushort*)(ws + (size_t)MROWS * FW * 2);          // +1 MiB
  ushort* psd = (ushort*)(ws + (size_t)MROWS * FW * 2
                             + (size_t)NPAD * FK * 2);           // +8 MiB
  ushort* W3p = (ushort*)(ws + (size_t)MROWS * FW * 2
                             + (size_t)NPAD * FK * 2
                             + (size_t)MROWS * PSDK * 2);        // +192 KiB

  prep_k<<<MROWS / 2 + (NPAD + HN) / 2, 256, 0, stream>>>(x, filt, W3, fh, Bt, W3p);
  gemm_psd_k<<<(MROWS / 64) * (NPAD / 128), 256, 0, stream>>>(fh, Bt, psd);
  head_gemm_k<<<MROWS / 16, 256, 0, stream>>>(psd, W3p, b3, out);
}

// Round 8
// 36.233 us; speedup vs baseline: 1.3152x; 1.0967x over previous
//
#include <hip/hip_runtime.h>
#include <hip/hip_bf16.h>

#define SIG   1000
#define MROWS 8192
#define FK    512    // folded K (500 used, padded)
#define FW    1024   // fold buffer width: [ce(512) | ho(512)]
#define NPAD  1024   // GEMM N: group0 = even-bin (cos,sin) pairs, group1 = odd-bin
#define PSDK  512    // psd padded columns (500 used) -> head GEMM K
#define HN    192    // head GEMM padded N (141 used)
#define NOUT  141
#define NT    16     // K-tiles per GEMM (512/32)

using f32x4  = __attribute__((ext_vector_type(4))) float;
using short8 = __attribute__((ext_vector_type(8))) short;

__device__ inline ushort f2bf(float f) {
  union { float f; unsigned u; } v; v.f = f;
  unsigned u = v.u;
  unsigned r = (u + 0x7FFFu + ((u >> 16) & 1u)) >> 16;   // RNE
  return (ushort)r;
}

// Rule-#18 hardened pipeline boundary: nothing (MFMA, ds_read, global_load_lds)
// may be scheduled across the waitcnt+barrier pair in either direction.
#define SYNC_BOUNDARY(WAITSTR)                         \
  do {                                                 \
    __builtin_amdgcn_sched_barrier(0);                 \
    asm volatile(WAITSTR ::: "memory");                \
    __builtin_amdgcn_s_barrier();                      \
    __builtin_amdgcn_sched_barrier(0);                 \
  } while (0)

// Merged prep: blocks [0,4096) do the radix-2 fold (2 rows each);
// blocks [4096, 4096+608) build Bt / W3p (2 weight-rows each).
__global__ __launch_bounds__(256) void prep_k(
    const float* __restrict__ x, const float* __restrict__ filt,
    const float* __restrict__ W3, ushort* __restrict__ fh,
    ushort* __restrict__ Bt, ushort* __restrict__ W3p) {
  const int tid = threadIdx.x;
  const int blk = blockIdx.x;
  if (blk < MROWS / 2) {
    // ---- fold: h[k]=x*filt; fh[r][k]=h[k]+h[k+500], fh[r][512+k]=h[k]-h[k+500]
    const int r = blk * 2 + (tid >> 7);
    const int c = tid & 127;               // float4 chunk within 512-col half
    ushort4 e = make_ushort4(0, 0, 0, 0);
    ushort4 o = make_ushort4(0, 0, 0, 0);
    if (c < 125) {
      const float4* xr = (const float4*)(x + (size_t)r * SIG);
      const float4* fr = (const float4*)filt;
      const float4 xl = xr[c],       fl = fr[c];
      const float4 xh = xr[c + 125], fv = fr[c + 125];
      float lx = xl.x * fl.x, ly = xl.y * fl.y, lz = xl.z * fl.z, lw = xl.w * fl.w;
      float hx = xh.x * fv.x, hy = xh.y * fv.y, hz = xh.z * fv.z, hw = xh.w * fv.w;
      e.x = f2bf(lx + hx); e.y = f2bf(ly + hy); e.z = f2bf(lz + hz); e.w = f2bf(lw + hw);
      o.x = f2bf(lx - hx); o.y = f2bf(ly - hy); o.z = f2bf(lz - hz); o.w = f2bf(lw - hw);
    }
    ((ushort4*)(fh + (size_t)r * FW))[c]      = e;
    ((ushort4*)(fh + (size_t)r * FW + FK))[c] = o;
  } else {
    // ---- weight build: rows [0,1024) -> Bt, [1024,1216) -> W3p
    const int row = (blk - MROWS / 2) * 2 + (tid >> 7);
    const int c   = tid & 127;             // ushort4 chunk: k = 4c..4c+3
    if (row < NPAD) {
      const int cg = row & 511, g = row >> 9;
      ushort4 o = make_ushort4(0, 0, 0, 0);
      if (cg < 500) {
        const int m = 2 * (cg >> 1) + g;
        const int trig = cg & 1;
        const float C = 6.28318530717958647692f / 1000.0f;
        ushort v[4];
#pragma unroll
        for (int j = 0; j < 4; ++j) {
          int ph = ((4 * c + j) * m) % 1000;
          float ang = ph * C;
          v[j] = f2bf(trig ? __sinf(ang) : __cosf(ang));
        }
        o = make_ushort4(v[0], v[1], v[2], v[3]);
      }
      ((ushort4*)(Bt + (size_t)row * FK))[c] = o;
    } else {
      const int n = row - NPAD;
      ushort4 o = make_ushort4(0, 0, 0, 0);
      if (n < NOUT && c < 125) {           // 4c+3 <= 499
        const float4 w = *(const float4*)(W3 + (size_t)n * 500 + 4 * c);
        o.x = f2bf(w.x); o.y = f2bf(w.y); o.z = f2bf(w.z); o.w = f2bf(w.w);
      }
      ((ushort4*)(W3p + (size_t)n * PSDK))[c] = o;
    }
  }
}

// Folded DFT GEMM + psd epilogue. M=8192, K=512, N=1024.
// 128x128 tile, 512 threads / 8 waves (4x2, wave 32x64 = 2x4 frags),
// grid 512 (2 blocks/CU, 16 waves/CU). Depth-2 pipeline: 3 LDS buffers,
// counted s_waitcnt vmcnt(2) across s_barrier, rule-#18 pinned boundaries.
__global__ __launch_bounds__(512, 4) void gemm_psd_k(
    const ushort* __restrict__ A, const ushort* __restrict__ Bt,
    ushort* __restrict__ psd) {
  __shared__ ushort lA[3][128 * 32];   // 3 x 8 KiB
  __shared__ ushort lB[3][128 * 32];   // 3 x 8 KiB
  const int tid  = threadIdx.x;
  const int wave = tid >> 6;
  const int lane = tid & 63;
  // bijective XCD swizzle: grid 512 = 8 xcd x 64; 8 bx-panels per XCD
  const int id  = blockIdx.x;
  const int xcd = id & 7, rr = id >> 3;
  const int bx  = xcd * 8 + (rr & 7);        // [0,64)
  const int by  = rr >> 3;                   // [0,8)
  const int row0 = bx * 128;
  const int n0   = by * 128;
  const int aoff = (by >= 4) ? FK : 0;       // ce vs ho half
  const int wm = (wave >> 1) * 32;           // 4 row-groups
  const int wn = (wave & 1) * 64;            // 2 col-groups
  const int lr = lane & 15;
  const int kg = (lane >> 4) * 8;

  // staging: A = 8 chunks of 1 KiB, B = 8 chunks; wave w stages A-chunk w, B-chunk w
  const int doff = wave * 1024;
  const int soff = doff + lane * 16;
  const int srow = soff >> 6;
  const int skb  = (soff & 63) >> 1;
  const ushort* gA = A  + (size_t)(row0 + srow) * FW + aoff + skb;
  const ushort* gB = Bt + (size_t)(n0   + srow) * FK + skb;

  auto STAGE = [&](int buf, int k0) {
    __builtin_amdgcn_global_load_lds(
        (const __attribute__((address_space(1))) void*)(gA + k0),
        (__attribute__((address_space(3))) void*)((char*)lA[buf] + doff), 16, 0, 0);
    __builtin_amdgcn_global_load_lds(
        (const __attribute__((address_space(1))) void*)(gB + k0),
        (__attribute__((address_space(3))) void*)((char*)lB[buf] + doff), 16, 0, 0);
  };

  f32x4 acc[2][4] = {};

  STAGE(0, 0);
  STAGE(1, 32);
  SYNC_BOUNDARY("s_waitcnt vmcnt(2)");   // buf0 ready, buf1's 2 loads in flight

#pragma unroll
  for (int kt = 0; kt < NT; ++kt) {
    const int cur = kt % 3;
    if (kt + 2 < NT) STAGE((kt + 2) % 3, (kt + 2) * 32);
    short8 a[2], b[4];
    const ushort* baseA = lA[cur];
    const ushort* baseB = lB[cur];
#pragma unroll
    for (int m = 0; m < 2; ++m)
      a[m] = *(const short8*)&baseA[(wm + m * 16 + lr) * 32 + kg];
#pragma unroll
    for (int n = 0; n < 4; ++n)
      b[n] = *(const short8*)&baseB[(wn + n * 16 + lr) * 32 + kg];
#pragma unroll
    for (int m = 0; m < 2; ++m)
#pragma unroll
      for (int n = 0; n < 4; ++n)
        acc[m][n] = __builtin_amdgcn_mfma_f32_16x16x32_bf16(a[m], b[n], acc[m][n], 0, 0, 0);
    if (kt < NT - 1) {
      if (kt + 2 < NT)
        SYNC_BOUNDARY("s_waitcnt vmcnt(2) lgkmcnt(0)");  // next buf ready, newest in flight
      else
        SYNC_BOUNDARY("s_waitcnt vmcnt(0) lgkmcnt(0)");  // tail drain
    }
  }

  // epilogue: C/D layout col=lane&15, row=(lane>>4)*4+j (m89/m91 verified)
  const int g = by >> 2;
  const int colpar = lane & 1;
#pragma unroll
  for (int m = 0; m < 2; ++m) {
#pragma unroll
    for (int n = 0; n < 4; ++n) {
#pragma unroll
      for (int j = 0; j < 4; ++j) {
        float v  = acc[m][n][j];
        float v2 = __shfl_xor(v, 1);             // sin partner of the pair
        if (!colpar) {
          int grow = row0 + wm + m * 16 + (lane >> 4) * 4 + j;
          int cg   = ((n0 + wn + n * 16 + lr) & 511);
          int mbin = (cg & ~1) + g;              // 2*pair + group
          psd[(size_t)grow * PSDK + mbin] = f2bf((v * v + v2 * v2) * 1e-6f);
        }
      }
    }
  }
}

// head: out[8192][141] = psd[:, :500] @ W3^T + b3 via bf16 MFMA.
// 16x192 tile, grid 512 (2 blocks/CU), 4 waves (wave 16x48 = 1x3 frags).
// Same depth-2 pipeline, rule-#18 pinned boundaries.
__global__ __launch_bounds__(256, 2) void head_gemm_k(
    const ushort* __restrict__ psd, const ushort* __restrict__ W3p,
    const float* __restrict__ b3, float* __restrict__ out) {
  __shared__ ushort lA[3][16 * 32];    // 3 x 1 KiB
  __shared__ ushort lB[3][HN * 32];    // 3 x 12 KiB
  const int tid  = threadIdx.x;
  const int wave = tid >> 6;
  const int lane = tid & 63;
  const int row0 = blockIdx.x * 16;
  const int wn = wave * 48;
  const int lr = lane & 15;
  const int kg = (lane >> 4) * 8;

  // staging: 13 chunks (A:1, B:12); wave w -> chunks {w, w+4, w+8, w+12} (<13)
  const ushort* gs[4];
  int doff[4], isa[4], valid[4];
#pragma unroll
  for (int j = 0; j < 4; ++j) {
    const int i = wave + 4 * j;
    valid[j] = (i < 13);
    const int ia  = (i == 0);
    const int idx = ia ? 0 : (i - 1);
    const int off = (ia ? 0 : idx * 1024) + lane * 16;
    const int row = off >> 6;
    const int kb  = (off & 63) >> 1;
    gs[j]   = ia ? (psd + (size_t)(row0 + row) * PSDK + kb)
                 : (W3p + (size_t)row * PSDK + kb);
    doff[j] = ia ? 0 : idx * 1024;
    isa[j]  = ia;
  }

  auto HSTAGE = [&](int buf, int k0) {
#pragma unroll
    for (int j = 0; j < 4; ++j) {
      if (valid[j]) {
        char* db = (isa[j] ? (char*)lA[buf] : (char*)lB[buf]) + doff[j];
        __builtin_amdgcn_global_load_lds(
            (const __attribute__((address_space(1))) void*)(gs[j] + k0),
            (__attribute__((address_space(3))) void*)db, 16, 0, 0);
      }
    }
  };

  f32x4 acc[3] = {};

  HSTAGE(0, 0);
  HSTAGE(1, 32);
  // wave 0 stages 4 chunks/buffer, waves 1-3 stage 3 (wave-uniform branch)
  __builtin_amdgcn_sched_barrier(0);
  if (wave == 0) asm volatile("s_waitcnt vmcnt(4)" ::: "memory");
  else           asm volatile("s_waitcnt vmcnt(3)" ::: "memory");
  __builtin_amdgcn_s_barrier();
  __builtin_amdgcn_sched_barrier(0);

#pragma unroll
  for (int kt = 0; kt < NT; ++kt) {
    const int cur = kt % 3;
    if (kt + 2 < NT) HSTAGE((kt + 2) % 3, (kt + 2) * 32);
    short8 a, b[3];
    const ushort* baseA = lA[cur];
    const ushort* baseB = lB[cur];
    a = *(const short8*)&baseA[lr * 32 + kg];
#pragma unroll
    for (int n = 0; n < 3; ++n)
      b[n] = *(const short8*)&baseB[(wn + n * 16 + lr) * 32 + kg];
#pragma unroll
    for (int n = 0; n < 3; ++n)
      acc[n] = __builtin_amdgcn_mfma_f32_16x16x32_bf16(a, b[n], acc[n], 0, 0, 0);
    if (kt < NT - 1) {
      __builtin_amdgcn_sched_barrier(0);
      if (kt + 2 < NT) {
        if (wave == 0) asm volatile("s_waitcnt vmcnt(4) lgkmcnt(0)" ::: "memory");
        else           asm volatile("s_waitcnt vmcnt(3) lgkmcnt(0)" ::: "memory");
      } else {
        asm volatile("s_waitcnt vmcnt(0) lgkmcnt(0)" ::: "memory");
      }
      __builtin_amdgcn_s_barrier();
      __builtin_amdgcn_sched_barrier(0);
    }
  }

#pragma unroll
  for (int n = 0; n < 3; ++n) {
#pragma unroll
    for (int j = 0; j < 4; ++j) {
      int gcol = wn + n * 16 + lr;
      if (gcol < NOUT) {
        int grow = row0 + (lane >> 4) * 4 + j;
        out[(size_t)grow * NOUT + gcol] = acc[n][j] + b3[gcol];
      }
    }
  }
}

extern "C" void kernel_launch(void* const* d_in, const int* in_sizes, int n_in,
                              void* d_out, int out_size, void* d_ws, size_t ws_size,
                              hipStream_t stream) {
  const float* x    = (const float*)d_in[0];
  const float* filt = (const float*)d_in[1];
  // d_in[2] (Wf), d_in[3] (Wfc) unused: DFT weights synthesized on device;
  // r2 = r1, i2 = -i1 algebraically so Wfc's GEMM is redundant.
  const float* W3   = (const float*)d_in[4];
  const float* b3   = (const float*)d_in[5];
  float* out = (float*)d_out;

  char* ws = (char*)d_ws;
  ushort* fh  = (ushort*)ws;                                     // 16 MiB
  ushort* Bt  = (ushort*)(ws + (size_t)MROWS * FW * 2);          // +1 MiB
  ushort* psd = (ushort*)(ws + (size_t)MROWS * FW * 2
                             + (size_t)NPAD * FK * 2);           // +8 MiB
  ushort* W3p = (ushort*)(ws + (size_t)MROWS * FW * 2
                             + (size_t)NPAD * FK * 2
                             + (size_t)MROWS * PSDK * 2);        // +192 KiB

  prep_k<<<MROWS / 2 + (NPAD + HN) / 2, 256, 0, stream>>>(x, filt, W3, fh, Bt, W3p);
  gemm_psd_k<<<(MROWS / 128) * (NPAD / 128), 512, 0, stream>>>(fh, Bt, psd);
  head_gemm_k<<<MROWS / 16, 256, 0, stream>>>(psd, W3p, b3, out);
}